// Round 16
// baseline (157.159 us; speedup 1.0000x reference)
//
#include <hip/hip_runtime.h>
#include <math.h>

#define BB   32
#define HH   56
#define WWI  56
#define CC   96
#define NHD  3
#define WSZ  7
#define SHF  3
#define NTK  49
#define NWIN 64
#define HDM  32
#define TOT  (BB*HH*WWI)               // 100352
#define QKSCALE 0.17677669529663687f
#define LEPS 1e-3f

typedef __attribute__((ext_vector_type(8))) short s8v;   // 8 bf16 (4 VGPRs)
typedef __attribute__((ext_vector_type(4))) float fx4;   // 4 fp32
typedef unsigned long long ull_t;

#define MFMA16(a,b,c) __builtin_amdgcn_mfma_f32_16x16x32_bf16((a),(b),(c),0,0,0)

__device__ __forceinline__ unsigned short f2bf(float f) {
    union { float f; unsigned u; } v; v.f = f;
    unsigned r = v.u + 0x7FFFu + ((v.u >> 16) & 1u);
    return (unsigned short)(r >> 16);
}

// sigmoid-form gelu (tanh approx): |err vs exact| <~2e-3, ~8 VALU ops vs ~28 for erff
__device__ __forceinline__ float gelu_t(float x) {
    float x3 = x * x * x;
    float z = -1.5957691216f * fmaf(0.044715f, x3, x);
    return x * __builtin_amdgcn_rcpf(1.f + __expf(z));
}

// windowed token id -> original flat token id (roll(-3,-3) + window partition)
__device__ __forceinline__ int wtok_to_orig(int wt) {
    int win = wt / NTK;
    int p   = wt - win * NTK;
    int b   = win >> 6;
    int w   = win & 63;
    int wi = w >> 3, wj = w & 7;
    int pi = p / WSZ, pj = p - pi * WSZ;
    int r = wi * WSZ + pi + SHF; if (r >= HH) r -= HH;
    int c = wj * WSZ + pj + SHF; if (c >= WWI) c -= WWI;
    return b * (HH * WWI) + r * WWI + c;
}

// LayerNorm in MFMA-A-fragment layout (reduction via shfl_xor 16/32)
__device__ __forceinline__ void ln_frag(const float* __restrict__ row,
                                        const float* __restrict__ gg,
                                        const float* __restrict__ bb,
                                        int g4, s8v ha[3])
{
    float h[24];
    #pragma unroll
    for (int ks = 0; ks < 3; ++ks) {
        fx4 v0 = *reinterpret_cast<const fx4*>(row + ks * 32 + g4 * 8);
        fx4 v1 = *reinterpret_cast<const fx4*>(row + ks * 32 + g4 * 8 + 4);
        h[ks*8+0]=v0.x; h[ks*8+1]=v0.y; h[ks*8+2]=v0.z; h[ks*8+3]=v0.w;
        h[ks*8+4]=v1.x; h[ks*8+5]=v1.y; h[ks*8+6]=v1.z; h[ks*8+7]=v1.w;
    }
    float s = 0.f, s2 = 0.f;
    #pragma unroll
    for (int j = 0; j < 24; ++j) { s += h[j]; s2 = fmaf(h[j], h[j], s2); }
    s  += __shfl_xor(s, 16);  s  += __shfl_xor(s, 32);
    s2 += __shfl_xor(s2, 16); s2 += __shfl_xor(s2, 32);
    const float mu = s * (1.f/CC);
    const float rs = rsqrtf(s2 * (1.f/CC) - mu * mu + LEPS);
    #pragma unroll
    for (int ks = 0; ks < 3; ++ks) {
        union { s8v v; unsigned short u[8]; } p;
        #pragma unroll
        for (int j = 0; j < 8; ++j) {
            int c = ks * 32 + g4 * 8 + j;
            p.u[j] = f2bf((h[ks*8+j] - mu) * rs * gg[c] + bb[c]);
        }
        ha[ks] = p.v;
    }
}

// ---------- P0: ALL weights frag-linearized (one wave-fragment = contiguous 1KB) ----------
// qwtf[((ck*6+nt)*3+ks)*512 + lane*8 + e] = qw[k*288 + n]  (n<96 prescaled)
//   n = ck*96+nt*16+(lane&15), k = ks*32+(lane>>4)*8+e
// pwtf[(nt*3+ks)*512 + lane*8 + e] = pw[k*96 + n],  n = nt*16+(lane&15), k = ks*32+(lane>>4)*8+e
// w1f[((ck*4+nt)*3+ks)*512 + ...] = w1[k*384 + n],  n = ck*64+nt*16+.., k = ks*32+..
// w2f[((ck*6+nt)*2+ks)*512 + ...] = w2[k*96 + n],   n = nt*16+.., k = ck*64+ks*32+..
extern "C" __global__ void p0_prep(const float* __restrict__ qw, const float* __restrict__ pw,
                                   const float* __restrict__ w1, const float* __restrict__ w2,
                                   const float* __restrict__ btab,
                                   unsigned short* __restrict__ wsw)
{
    int i = blockIdx.x * 256 + threadIdx.x;
    if (i < 27648) {                       // qwtf frag-linear
        int e = i & 7, f = i >> 3;
        int lane = f & 63, fid = f >> 6;   // fid 0..53
        int ks = fid % 3, t = fid / 3;
        int nt = t % 6, ck = t / 6;
        int n = ck * 96 + nt * 16 + (lane & 15);
        int k = ks * 32 + (lane >> 4) * 8 + e;
        float v = qw[k * 288 + n];
        if (n < 96) v *= QKSCALE;
        wsw[i] = f2bf(v);
    } else if (i < 36864) {                // pwtf frag-linear
        int j = i - 27648;
        int e = j & 7, f = j >> 3;
        int lane = f & 63, fid = f >> 6;   // fid 0..17
        int ks = fid % 3, nt = fid / 3;
        int n = nt * 16 + (lane & 15);
        int k = ks * 32 + (lane >> 4) * 8 + e;
        wsw[i] = f2bf(pw[k * 96 + n]);
    } else if (i < 73728) {                // w1f frag-linear
        int j = i - 36864;
        int e = j & 7, f = j >> 3;
        int lane = f & 63, fid = f >> 6;
        int ks = fid % 3, t = fid / 3;
        int nt = t & 3, ck = t >> 2;
        int n = ck * 64 + nt * 16 + (lane & 15);
        int k = ks * 32 + (lane >> 4) * 8 + e;
        wsw[i] = f2bf(w1[k * 384 + n]);
    } else if (i < 110592) {               // w2f frag-linear
        int j = i - 73728;
        int e = j & 7, f = j >> 3;
        int lane = f & 63, fid = f >> 6;
        int ks = fid & 1, t = fid >> 1;
        int nt = t % 6, ck = t / 6;
        int n = nt * 16 + (lane & 15);
        int k = ck * 64 + ks * 32 + (lane >> 4) * 8 + e;
        wsw[i] = f2bf(w2[k * 96 + n]);
    } else if (i < 148224) {               // BM table (fp32)
        float* bm = (float*)(wsw + 110592);
        int j = i - 110592;
        int n = j & 63, mh = j >> 6;
        int m = mh % 49, t = mh / 49;
        int hd = t % 3, cls = t / 3;       // cls = (wi==7)*2 + (wj==7)
        float val = 0.f;
        if (n < 49) {
            int it = m / 7, jt = m - it * 7;
            int iu = n / 7, ju = n - iu * 7;
            int li  = (cls & 2) ? (it < 4 ? 1 : 2) : 0;
            int lj  = (cls & 1) ? (jt < 4 ? 1 : 2) : 0;
            int lui = (cls & 2) ? (iu < 4 ? 1 : 2) : 0;
            int luj = (cls & 1) ? (ju < 4 ? 1 : 2) : 0;
            int bidx = (jt - ju + 6) * 13 + (it - iu + 6);
            val = btab[bidx * 3 + hd] + ((li*3+lj) == (lui*3+luj) ? 0.f : -100.f);
        }
        bm[j] = val;
    }
}

// ---------- K1: barrier-free gather + LN1(frag) + QKV MFMA -> qkvb bf16 ----------
// Zero LDS, zero barriers: A-frags in regs, B-frags = contiguous 1KB loads.
extern "C" __global__ void __launch_bounds__(256, 3) k1_qkv(
    const float* __restrict__ x, const float* __restrict__ g1, const float* __restrict__ b1,
    const unsigned short* __restrict__ qwtf, const float* __restrict__ qb,
    unsigned short* __restrict__ qkvb)
{
    const int tid = threadIdx.x, wave = tid >> 6, lane = tid & 63;
    const int l15 = lane & 15, g4 = lane >> 4;
    const int row0 = blockIdx.x * 64 + wave * 16;

    s8v ha[3];
    {
        const int orig = wtok_to_orig(row0 + l15);
        ln_frag(x + (size_t)orig * CC, g1, b1, g4, ha);
    }

    #pragma unroll 1
    for (int ck = 0; ck < 3; ++ck) {
        fx4 acc[6];
        #pragma unroll
        for (int nt = 0; nt < 6; ++nt) acc[nt] = (fx4){0.f,0.f,0.f,0.f};
        #pragma unroll
        for (int ks = 0; ks < 3; ++ks) {
            #pragma unroll
            for (int nt = 0; nt < 6; ++nt) {
                s8v b = *reinterpret_cast<const s8v*>(
                    &qwtf[(((ck * 6 + nt) * 3 + ks) * 64 + lane) * 8]);
                acc[nt] = MFMA16(ha[ks], b, acc[nt]);
            }
        }
        const int rowb = row0 + g4 * 4;
        const float qmul = (ck == 0) ? QKSCALE : 1.f;   // qb scale matches scaled qwtf
        #pragma unroll
        for (int nt = 0; nt < 6; ++nt) {
            const int col = ck * 96 + nt * 16 + l15;
            const float qbc = qb[col] * qmul;
            #pragma unroll
            for (int r = 0; r < 4; ++r)
                qkvb[(size_t)(rowb + r) * 288 + col] = f2bf(acc[nt][r] + qbc);
        }
    }
}

// ---------- K2: MFMA attention on bf16 qkv (R12 form, unchanged) ----------
extern "C" __global__ void __launch_bounds__(64, 2) k2_attn(
    unsigned short* __restrict__ qkvb, const float* __restrict__ bm)
{
    __shared__ unsigned short P[64][72];   // 9216 B
    const int lane = threadIdx.x;
    const int l15 = lane & 15, g4 = lane >> 4;
    const int task = blockIdx.x;
    const int win = task / 3, h = task - win * 3;
    const int g0  = win * NTK;
    const int w   = win & 63;
    const int cls = (((w >> 3) == 7) ? 2 : 0) + (((w & 7) == 7) ? 1 : 0);
    const float* BMh = bm + ((size_t)(cls * 3 + h)) * 49 * 64;

    s8v aq[4], bk[4];
    #pragma unroll
    for (int mt = 0; mt < 4; ++mt) {
        int tok = mt * 16 + l15; if (tok > 48) tok = 48;
        const unsigned short* qp = &qkvb[(size_t)(g0 + tok) * 288 + h * HDM + g4 * 8];
        aq[mt] = *reinterpret_cast<const s8v*>(qp);        // Q (pre-scaled)
        bk[mt] = *reinterpret_cast<const s8v*>(qp + 96);   // K
    }

    fx4 sc[4][4];
    #pragma unroll
    for (int mt = 0; mt < 4; ++mt)
        #pragma unroll
        for (int nt = 0; nt < 4; ++nt)
            sc[mt][nt] = MFMA16(aq[mt], bk[nt], ((fx4){0.f,0.f,0.f,0.f}));

    #pragma unroll
    for (int mt = 0; mt < 4; ++mt) {
        #pragma unroll
        for (int r = 0; r < 4; ++r) {
            const int m = mt * 16 + g4 * 4 + r;
            const int mc = m > 48 ? 48 : m;
            float rs1 = 0.f;
            #pragma unroll
            for (int nt = 0; nt < 4; ++nt) {
                const int n = nt * 16 + l15;
                float s = sc[mt][nt][r] + BMh[mc * 64 + n];
                float e = (n < NTK) ? __expf(s) : 0.f;
                sc[mt][nt][r] = e;
                rs1 += e;
            }
            rs1 += __shfl_xor(rs1, 1); rs1 += __shfl_xor(rs1, 2);
            rs1 += __shfl_xor(rs1, 4); rs1 += __shfl_xor(rs1, 8);
            const float iv1 = 1.f / rs1;
            float rs2 = 0.f;
            #pragma unroll
            for (int nt = 0; nt < 4; ++nt) {
                const int n = nt * 16 + l15;
                float e2 = (n < NTK) ? __expf(sc[mt][nt][r] * iv1) : 0.f;
                sc[mt][nt][r] = e2;
                rs2 += e2;
            }
            rs2 += __shfl_xor(rs2, 1); rs2 += __shfl_xor(rs2, 2);
            rs2 += __shfl_xor(rs2, 4); rs2 += __shfl_xor(rs2, 8);
            const float iv2 = 1.f / rs2;
            #pragma unroll
            for (int nt = 0; nt < 4; ++nt)
                P[m][nt * 16 + l15] = f2bf(sc[mt][nt][r] * iv2);
        }
    }
    __syncthreads();

    fx4 oc[4][2];
    #pragma unroll
    for (int mt = 0; mt < 4; ++mt) { oc[mt][0] = (fx4){0.f,0.f,0.f,0.f}; oc[mt][1] = (fx4){0.f,0.f,0.f,0.f}; }
    #pragma unroll
    for (int ks = 0; ks < 2; ++ks) {
        s8v vb[2];
        #pragma unroll
        for (int nt = 0; nt < 2; ++nt) {
            union { s8v v; unsigned short u[8]; } pv;
            #pragma unroll
            for (int j = 0; j < 8; ++j) {
                int tok = ks * 32 + g4 * 8 + j; if (tok > 48) tok = 48;
                pv.u[j] = qkvb[(size_t)(g0 + tok) * 288 + 192 + h * HDM + nt * 16 + l15];
            }
            vb[nt] = pv.v;
        }
        #pragma unroll
        for (int mt = 0; mt < 4; ++mt) {
            s8v pa = *reinterpret_cast<const s8v*>(&P[mt * 16 + l15][ks * 32 + g4 * 8]);
            oc[mt][0] = MFMA16(pa, vb[0], oc[mt][0]);
            oc[mt][1] = MFMA16(pa, vb[1], oc[mt][1]);
        }
    }
    #pragma unroll
    for (int mt = 0; mt < 4; ++mt) {
        #pragma unroll
        for (int r = 0; r < 4; ++r) {
            const int m = mt * 16 + g4 * 4 + r;
            if (m < NTK) {
                qkvb[(size_t)(g0 + m) * 288 + h * HDM + l15]      = f2bf(oc[mt][0][r]);
                qkvb[(size_t)(g0 + m) * 288 + h * HDM + 16 + l15] = f2bf(oc[mt][1][r]);
            }
        }
    }
}

// ---------- K2b: barrier-free proj GEMM + residual + un-shift scatter ----------
// Zero LDS/barriers: A-frags direct from qkvb, B-frags from frag-linear pwtf.
extern "C" __global__ void __launch_bounds__(256, 3) k2b_proj(
    const unsigned short* __restrict__ qkvb, const unsigned short* __restrict__ pwtf,
    const float* __restrict__ pb, const float* __restrict__ x, float* __restrict__ out)
{
    const int tid = threadIdx.x, wave = tid >> 6, lane = tid & 63;
    const int l15 = lane & 15, g4 = lane >> 4;
    const int row0 = blockIdx.x * 64 + wave * 16;

    const unsigned short* arow = qkvb + (size_t)(row0 + l15) * 288 + g4 * 8;
    s8v a[3];
    a[0] = *reinterpret_cast<const s8v*>(arow);
    a[1] = *reinterpret_cast<const s8v*>(arow + 32);
    a[2] = *reinterpret_cast<const s8v*>(arow + 64);

    fx4 acc[6];
    #pragma unroll
    for (int nt = 0; nt < 6; ++nt) acc[nt] = (fx4){0.f,0.f,0.f,0.f};
    #pragma unroll
    for (int ks = 0; ks < 3; ++ks) {
        #pragma unroll
        for (int nt = 0; nt < 6; ++nt) {
            s8v b = *reinterpret_cast<const s8v*>(&pwtf[((nt * 3 + ks) * 64 + lane) * 8]);
            acc[nt] = MFMA16(a[ks], b, acc[nt]);
        }
    }
    int orig[4];
    #pragma unroll
    for (int r = 0; r < 4; ++r)
        orig[r] = wtok_to_orig(row0 + g4 * 4 + r);
    #pragma unroll
    for (int nt = 0; nt < 6; ++nt) {
        const int col = nt * 16 + l15;
        const float pbc = pb[col];
        #pragma unroll
        for (int r = 0; r < 4; ++r) {
            const size_t idx = (size_t)orig[r] * CC + col;
            out[idx] = acc[nt][r] + pbc + x[idx];
        }
    }
}

// ---------- K3: barrier-free MLP, TWO 16-token tiles per wave ----------
// Each B-frag load feeds 2 MFMAs -> L2 weight traffic per token halves.
// fc1 restructured per-nt (B once -> 2 MFMAs -> gelu both) to cap live regs.
#define LDA 72
extern "C" __global__ void __launch_bounds__(256, 3) k3_mlp(
    float* __restrict__ xio, const float* __restrict__ g2, const float* __restrict__ b2,
    const unsigned short* __restrict__ w1f, const float* __restrict__ bf1,
    const unsigned short* __restrict__ w2f, const float* __restrict__ bf2)
{
    __shared__ unsigned short Ac[128 * LDA];   // 18432 B, wave-private rows
    const int tid = threadIdx.x, wave = tid >> 6, lane = tid & 63;
    const int l15 = lane & 15, g4 = lane >> 4;
    const int row0 = blockIdx.x * 128 + wave * 32;

    s8v ha0[3], ha1[3];
    ln_frag(xio + (size_t)(row0 + l15) * CC,      g2, b2, g4, ha0);
    ln_frag(xio + (size_t)(row0 + 16 + l15) * CC, g2, b2, g4, ha1);

    fx4 oa0[6], oa1[6];
    #pragma unroll
    for (int nt = 0; nt < 6; ++nt) { oa0[nt] = (fx4){0.f,0.f,0.f,0.f}; oa1[nt] = (fx4){0.f,0.f,0.f,0.f}; }

    #pragma unroll 1
    for (int ck = 0; ck < 6; ++ck) {
        // fc1: per nt, load B once -> 2 MFMAs -> gelu both -> Ac
        #pragma unroll
        for (int nt = 0; nt < 4; ++nt) {
            fx4 aA = (fx4){0.f,0.f,0.f,0.f}, aB = (fx4){0.f,0.f,0.f,0.f};
            #pragma unroll
            for (int ks = 0; ks < 3; ++ks) {
                s8v b = *reinterpret_cast<const s8v*>(
                    &w1f[(((ck * 4 + nt) * 3 + ks) * 64 + lane) * 8]);
                aA = MFMA16(ha0[ks], b, aA);
                aB = MFMA16(ha1[ks], b, aB);
            }
            const float bb = bf1[ck * 64 + nt * 16 + l15];
            #pragma unroll
            for (int r = 0; r < 4; ++r) {
                Ac[(wave*32 +      g4*4 + r) * LDA + nt*16 + l15] = f2bf(gelu_t(gelu_t(aA[r] + bb)));
                Ac[(wave*32 + 16 + g4*4 + r) * LDA + nt*16 + l15] = f2bf(gelu_t(gelu_t(aB[r] + bb)));
            }
        }
        // fc2: B once -> 2 MFMAs (Ac wave-private: in-wave lgkmcnt ordering)
        #pragma unroll
        for (int ks = 0; ks < 2; ++ks) {
            s8v pA = *reinterpret_cast<const s8v*>(&Ac[(wave*32 +      l15)*LDA + ks*32 + g4*8]);
            s8v pB = *reinterpret_cast<const s8v*>(&Ac[(wave*32 + 16 + l15)*LDA + ks*32 + g4*8]);
            #pragma unroll
            for (int nt = 0; nt < 6; ++nt) {
                s8v b = *reinterpret_cast<const s8v*>(
                    &w2f[(((ck * 6 + nt) * 2 + ks) * 64 + lane) * 8]);
                oa0[nt] = MFMA16(pA, b, oa0[nt]);
                oa1[nt] = MFMA16(pB, b, oa1[nt]);
            }
        }
    }

    #pragma unroll
    for (int u = 0; u < 2; ++u) {
        const int rowb = row0 + u * 16 + g4 * 4;
        #pragma unroll
        for (int nt = 0; nt < 6; ++nt) {
            const int col = nt * 16 + l15;
            const float bb = bf2[col];
            #pragma unroll
            for (int r = 0; r < 4; ++r) {
                const size_t idx = (size_t)(rowb + r) * CC + col;
                const float ov = (u == 0) ? oa0[nt][r] : oa1[nt][r];
                xio[idx] = xio[idx] + ov + bb;
            }
        }
    }
}

extern "C" void kernel_launch(void* const* d_in, const int* in_sizes, int n_in,
                              void* d_out, int out_size, void* d_ws, size_t ws_size,
                              hipStream_t stream)
{
    const float* x    = (const float*)d_in[0];
    const float* n1g  = (const float*)d_in[1];
    const float* n1b  = (const float*)d_in[2];
    const float* qw   = (const float*)d_in[3];
    const float* qb   = (const float*)d_in[4];
    const float* btab = (const float*)d_in[5];
    const float* pw   = (const float*)d_in[6];
    const float* pb   = (const float*)d_in[7];
    const float* n2g  = (const float*)d_in[8];
    const float* n2b  = (const float*)d_in[9];
    const float* w1   = (const float*)d_in[10];
    const float* bf1  = (const float*)d_in[11];
    const float* w2   = (const float*)d_in[12];
    const float* bf2  = (const float*)d_in[13];
    float* out = (float*)d_out;

    unsigned short* qkvb = (unsigned short*)d_ws;                 // TOT*288 bf16 = 57.8 MB
    unsigned short* wbf  = qkvb + (size_t)TOT * 288;
    unsigned short* qwtf = wbf;                                   // 27648 frag-linear
    unsigned short* pwtf = qwtf + 27648;                          // 9216 frag-linear
    unsigned short* w1f  = pwtf + 9216;                           // 36864 frag-linear
    unsigned short* w2f  = w1f + 36864;                           // 36864 frag-linear
    float* bmt = (float*)(wbf + 110592);                          // [4][3][49][64]

    p0_prep <<<579, 256, 0, stream>>>(qw, pw, w1, w2, btab, wbf);
    k1_qkv  <<<TOT/64, 256, 0, stream>>>(x, n1g, n1b, qwtf, qb, qkvb);
    k2_attn <<<BB*NWIN*NHD, 64, 0, stream>>>(qkvb, bmt);
    k2b_proj<<<TOT/64, 256, 0, stream>>>(qkvb, pwtf, pb, x, out);
    k3_mlp  <<<TOT/128, 256, 0, stream>>>(out, n2g, n2b, w1f, bf1, w2f, bf2);
}